// Round 9
// baseline (164.555 us; speedup 1.0000x reference)
//
#include <hip/hip_runtime.h>
#include <stdint.h>

typedef __attribute__((ext_vector_type(8))) short bf16x8;
typedef __attribute__((ext_vector_type(4))) short s16x4;
typedef __attribute__((ext_vector_type(4))) float f32x4;
typedef __attribute__((ext_vector_type(16))) float f32x16;

__device__ __forceinline__ ushort f2bf(float f) {
  union { float f; uint32_t u; } c; c.f = f;
  uint32_t r = (c.u + 0x7fffu + ((c.u >> 16) & 1u)) >> 16;
  return (ushort)r;
}

__device__ __forceinline__ float bf2f(ushort u) {
  return __uint_as_float((uint32_t)u << 16);
}

__device__ __forceinline__ void gload16(const void* g, void* l) {
  __builtin_amdgcn_global_load_lds(
      (const __attribute__((address_space(1))) void*)g,
      (__attribute__((address_space(3))) void*)l, 16, 0, 0);
}

__device__ __forceinline__ unsigned lds_addr(const void* p) {
  return (unsigned)(uintptr_t)(__attribute__((address_space(3))) const char*)p;
}

__device__ __forceinline__ uint32_t cvtpk(float lo, float hi) {
  uint32_t d;
  asm("v_cvt_pk_bf16_f32 %0, %1, %2" : "=v"(d) : "v"(lo), "v"(hi));
  return d;
}

// ---------------- fused prep: LN(q) + cast k,v + cast 4 weights ----------------
__global__ __launch_bounds__(256) void prep_kernel(
    const float* __restrict__ q, const float* __restrict__ k,
    const float* __restrict__ v, const float* __restrict__ w_q,
    const float* __restrict__ w_k, const float* __restrict__ w_v,
    const float* __restrict__ w_o, const float* __restrict__ ln_g,
    const float* __restrict__ ln_b,
    ushort* __restrict__ qn, ushort* __restrict__ kb, ushort* __restrict__ vb,
    ushort* __restrict__ wqb, ushort* __restrict__ wkb,
    ushort* __restrict__ wvb, ushort* __restrict__ wob) {
  const int bid = blockIdx.x;
  const int t = threadIdx.x;
  if (bid < 4096) {
    const int row = bid;
    const float4 val = ((const float4*)(q + (size_t)row * 1024))[t];
    float s  = val.x + val.y + val.z + val.w;
    float s2 = val.x*val.x + val.y*val.y + val.z*val.z + val.w*val.w;
    #pragma unroll
    for (int off = 1; off < 64; off <<= 1) {
      s  += __shfl_xor(s,  off);
      s2 += __shfl_xor(s2, off);
    }
    __shared__ float red[8];
    const int wave = t >> 6, lane = t & 63;
    if (lane == 0) { red[wave*2] = s; red[wave*2+1] = s2; }
    __syncthreads();
    s  = red[0] + red[2] + red[4] + red[6];
    s2 = red[1] + red[3] + red[5] + red[7];
    const float mu = s * (1.0f/1024.0f);
    const float var = s2 * (1.0f/1024.0f) - mu*mu;
    const float rs = rsqrtf(var + 1e-6f);
    const float4 gg = ((const float4*)ln_g)[t];
    const float4 bb = ((const float4*)ln_b)[t];
    ushort4 o;
    o.x = f2bf((val.x - mu) * rs * gg.x + bb.x);
    o.y = f2bf((val.y - mu) * rs * gg.y + bb.y);
    o.z = f2bf((val.z - mu) * rs * gg.z + bb.z);
    o.w = f2bf((val.w - mu) * rs * gg.w + bb.w);
    ((ushort4*)(qn + (size_t)row * 1024))[t] = o;
    return;
  }
  const float* in; ushort* out; int i;
  if (bid < 12288) {
    const int idx = bid - 4096;
    const bool isv = idx >= 4096;
    in  = isv ? v : k;
    out = isv ? vb : kb;
    i = (idx & 4095) * 256 + t;
  } else {
    const int idx = bid - 12288;
    const int w = idx >> 10;
    in  = w == 0 ? w_q : (w == 1 ? w_k : (w == 2 ? w_v : w_o));
    out = w == 0 ? wqb : (w == 1 ? wkb : (w == 2 ? wvb : wob));
    i = (idx & 1023) * 256 + t;
  }
  const float4 val = ((const float4*)in)[i];
  ushort4 o;
  o.x = f2bf(val.x); o.y = f2bf(val.y); o.z = f2bf(val.z); o.w = f2bf(val.w);
  ((ushort4*)out)[i] = o;
}

// ---------------- mask tile flags (64x64 granularity) ----------------
__global__ __launch_bounds__(256) void mask_flags(
    const int* __restrict__ mask, int* __restrict__ flags) {
  const int qt = blockIdx.y, kt = blockIdx.x;
  const int t = threadIdx.x;
  const int* p = mask + (size_t)(qt * 64 + (t >> 2)) * 2048 + kt * 64 + (t & 3) * 16;
  int ok = 1;
  #pragma unroll
  for (int i = 0; i < 4; i++) {
    const int4 m = ((const int4*)p)[i];
    ok &= (m.x != 0) & (m.y != 0) & (m.z != 0) & (m.w != 0);
  }
  __shared__ int sok;
  if (t == 0) sok = 1;
  __syncthreads();
  if (!ok) atomicAnd(&sok, 0);
  __syncthreads();
  if (t == 0) flags[qt * 32 + kt] = sok;
}

// ---------------- QKV GEMM (R4-proven 4-buffer pipeline) ----------------
__global__ __launch_bounds__(256) void gemm3(
    const ushort* __restrict__ A0, const ushort* __restrict__ W0, ushort* __restrict__ C0,
    const ushort* __restrict__ A1, const ushort* __restrict__ W1, ushort* __restrict__ C1,
    const ushort* __restrict__ A2, const ushort* __restrict__ W2, ushort* __restrict__ C2,
    float qscale) {
  __shared__ ushort As[4][4096];
  __shared__ ushort Bs[4][4096];
  const int t = threadIdx.x, lane = t & 63, wave = t >> 6;
  const int wr = wave >> 1, wc = wave & 1;
  const int lr = lane & 15, lg = lane >> 4;
  const int brow = blockIdx.y * 128, bcol = blockIdx.x * 128;
  const int z = blockIdx.z;
  const ushort* A = z == 0 ? A0 : (z == 1 ? A1 : A2);
  const ushort* W = z == 0 ? W0 : (z == 1 ? W1 : W2);
  ushort*      C = z == 0 ? C0 : (z == 1 ? C1 : C2);
  const float sc = (z == 0) ? qscale : 1.0f;
  f32x4 acc[4][4] = {};
  const ushort* gA = A + (size_t)(brow + (t >> 2)) * 1024 + (t & 3) * 8;
  const ushort* gB = W + (size_t)(bcol + (t >> 2)) * 1024 + (t & 3) * 8;
  const int woff = wave * 1024;

#define G_ISSUE(S) { \
    char* la = (char*)As + ((S) & 3) * 8192 + woff; \
    char* lb = (char*)Bs + ((S) & 3) * 8192 + woff; \
    const ushort* ap_ = gA + (S) * 32; \
    const ushort* bp_ = gB + (S) * 32; \
    gload16(ap_, la); gload16(ap_ + 64 * 1024, la + 4096); \
    gload16(bp_, lb); gload16(bp_ + 64 * 1024, lb + 4096); }

#define G_COMPUTE(S) { \
    const ushort* as_ = As[(S) & 3]; \
    const ushort* bs_ = Bs[(S) & 3]; \
    bf16x8 af[4], bfr[4]; \
    _Pragma("unroll") for (int i = 0; i < 4; i++) \
      af[i]  = *(const bf16x8*)&as_[(wr*64 + i*16 + lr) * 32 + lg*8]; \
    _Pragma("unroll") for (int i = 0; i < 4; i++) \
      bfr[i] = *(const bf16x8*)&bs_[(wc*64 + i*16 + lr) * 32 + lg*8]; \
    _Pragma("unroll") for (int mi = 0; mi < 4; mi++) \
      _Pragma("unroll") for (int ni = 0; ni < 4; ni++) \
        acc[mi][ni] = __builtin_amdgcn_mfma_f32_16x16x32_bf16(af[mi], bfr[ni], acc[mi][ni], 0, 0, 0); }

  G_ISSUE(0); G_ISSUE(1); G_ISSUE(2);
  for (int s = 0; s < 30; ++s) {
    asm volatile("s_waitcnt vmcnt(8)" ::: "memory");
    __builtin_amdgcn_s_barrier();
    if (s < 29) G_ISSUE(s + 3);
    G_COMPUTE(s);
  }
  asm volatile("s_waitcnt vmcnt(4)" ::: "memory");
  __builtin_amdgcn_s_barrier();
  G_COMPUTE(30);
  asm volatile("s_waitcnt vmcnt(0)" ::: "memory");
  __builtin_amdgcn_s_barrier();
  G_COMPUTE(31);
#undef G_ISSUE
#undef G_COMPUTE

  #pragma unroll
  for (int mi = 0; mi < 4; mi++) {
    #pragma unroll
    for (int ni = 0; ni < 4; ni++) {
      #pragma unroll
      for (int r = 0; r < 4; r++) {
        const size_t row = brow + wr*64 + mi*16 + lg*4 + r;
        const size_t col = bcol + wc*64 + ni*16 + lr;
        C[row * 1024 + col] = f2bf(acc[mi][ni][r] * sc);
      }
    }
  }
}

// ---------------- Final GEMM: BM=64, fused residual (R8-proven) ----------------
__global__ __launch_bounds__(256) void gemm_bm64(
    const ushort* __restrict__ A, const ushort* __restrict__ W,
    float* __restrict__ Cf, const float* __restrict__ resid) {
  __shared__ ushort As[4][2048];
  __shared__ ushort Bs[4][4096];
  const int t = threadIdx.x, lane = t & 63, wave = t >> 6;
  const int wr = wave >> 1, wc = wave & 1;
  const int lr = lane & 15, lg = lane >> 4;
  const int brow = blockIdx.y * 64, bcol = blockIdx.x * 128;
  f32x4 acc[2][4] = {};
  const ushort* gA = A + (size_t)(brow + (t >> 2)) * 1024 + (t & 3) * 8;
  const ushort* gB = W + (size_t)(bcol + (t >> 2)) * 1024 + (t & 3) * 8;
  const int woff = wave * 1024;

#define G_ISSUE(S) { \
    char* la = (char*)As + ((S) & 3) * 4096 + woff; \
    char* lb = (char*)Bs + ((S) & 3) * 8192 + woff; \
    const ushort* ap_ = gA + (S) * 32; \
    const ushort* bp_ = gB + (S) * 32; \
    gload16(ap_, la); \
    gload16(bp_, lb); gload16(bp_ + 64 * 1024, lb + 4096); }

#define G_COMPUTE(S) { \
    const ushort* as_ = As[(S) & 3]; \
    const ushort* bs_ = Bs[(S) & 3]; \
    bf16x8 af[2], bfr[4]; \
    _Pragma("unroll") for (int i = 0; i < 2; i++) \
      af[i]  = *(const bf16x8*)&as_[(wr*32 + i*16 + lr) * 32 + lg*8]; \
    _Pragma("unroll") for (int i = 0; i < 4; i++) \
      bfr[i] = *(const bf16x8*)&bs_[(wc*64 + i*16 + lr) * 32 + lg*8]; \
    _Pragma("unroll") for (int mi = 0; mi < 2; mi++) \
      _Pragma("unroll") for (int ni = 0; ni < 4; ni++) \
        acc[mi][ni] = __builtin_amdgcn_mfma_f32_16x16x32_bf16(af[mi], bfr[ni], acc[mi][ni], 0, 0, 0); }

  G_ISSUE(0); G_ISSUE(1); G_ISSUE(2);
  for (int s = 0; s < 30; ++s) {
    asm volatile("s_waitcnt vmcnt(6)" ::: "memory");
    __builtin_amdgcn_s_barrier();
    if (s < 29) G_ISSUE(s + 3);
    G_COMPUTE(s);
  }
  asm volatile("s_waitcnt vmcnt(3)" ::: "memory");
  __builtin_amdgcn_s_barrier();
  G_COMPUTE(30);
  asm volatile("s_waitcnt vmcnt(0)" ::: "memory");
  __builtin_amdgcn_s_barrier();
  G_COMPUTE(31);
#undef G_ISSUE
#undef G_COMPUTE

  #pragma unroll
  for (int mi = 0; mi < 2; mi++) {
    #pragma unroll
    for (int ni = 0; ni < 4; ni++) {
      #pragma unroll
      for (int r = 0; r < 4; r++) {
        const size_t row = brow + wr*32 + mi*16 + lg*4 + r;
        const size_t col = bcol + wc*64 + ni*16 + lr;
        Cf[row * 1024 + col] = acc[mi][ni][r] + resid[row * 1024 + col];
      }
    }
  }
}

// ---------------- Flash attention: R7 body + KV-split x2, 32KB LDS ----------------
// Grid (32 = 16 qb x 2 split, 16 h, 2 b) = 1024 blocks -> 4 blocks/CU (LDS 4x32=128K).
// K/V double-buffered, 1-ahead prefetch, vmcnt(0)+barrier per tile.
// m=0 softmax (exact), l via MFMA; writes unnormalized partial O + l per split.
__global__ __launch_bounds__(256) void flash_attn(
    const ushort* __restrict__ Qp, const ushort* __restrict__ Kp,
    const ushort* __restrict__ Vp, const int* __restrict__ mask,
    const int* __restrict__ tflags,
    ushort* __restrict__ P0, ushort* __restrict__ P1,
    float* __restrict__ l0, float* __restrict__ l1) {
  const int L = 2048;
  const int qb = blockIdx.x >> 1, split = blockIdx.x & 1;
  const int h = blockIdx.y, b = blockIdx.z;
  const int t = threadIdx.x, lane = t & 63, wave = t >> 6;
  const int l31 = lane & 31, hi = lane >> 5;
  __shared__ ushort Ks[2][4096];
  __shared__ ushort Vs[2][4096];
  const size_t base = (size_t)b * L * 1024 + h * 64;
  const int qw0 = qb * 128 + wave * 32;
  const int T0 = split * 16;

  bf16x8 qf[4];
  #pragma unroll
  for (int kc = 0; kc < 4; kc++)
    qf[kc] = *(const bf16x8*)(Qp + base + (size_t)(qw0 + l31) * 1024 + kc*16 + hi*8);

  f32x16 accO0 = {0.f}, accO1 = {0.f}, accL = {0.f};
  const bf16x8 onef = {16256, 16256, 16256, 16256, 16256, 16256, 16256, 16256};

  const int r3 = (lane >> 3) & 7;
  const int c3 = (lane & 7) ^ r3;
  const ushort* gK = Kp + base + (size_t)(wave*8 + r3) * 1024 + c3 * 8;
  const int sv = t >> 3, hv = t & 7;
  const int vkv = (sv >> 2) * 4 + (hv >> 1);
  const int vd  = (sv & 3) * 16 + (hv & 1) * 8;
  const ushort* gV = Vp + base + (size_t)vkv * 1024 + vd;

  const unsigned vbase = lds_addr((const char*)Vs) + hi * 1024 +
                         ((lane >> 4) & 1) * 128 + (lane & 15) * 8;

#define STAGE(TILE, BUF) { \
    char* kb_ = (char*)Ks[BUF] + wave * 1024; \
    const ushort* gk_ = gK + (size_t)(TILE) * 65536; \
    gload16(gk_, kb_); gload16(gk_ + 32*1024, kb_ + 4096); \
    char* vb_ = (char*)Vs[BUF] + wave * 1024; \
    const ushort* gv_ = gV + (size_t)(TILE) * 65536; \
    gload16(gv_, vb_); gload16(gv_ + 32*1024, vb_ + 4096); }

  STAGE(T0, 0);
  const int flagBase = (qb * 2 + (wave >> 1)) * 32;

  for (int s = 0; s < 16; ++s) {
    asm volatile("s_waitcnt vmcnt(0)" ::: "memory");
    __builtin_amdgcn_s_barrier();
    if (s + 1 < 16) { STAGE(T0 + s + 1, (s + 1) & 1); }

    const int kvt = T0 + s;
    const char* KsB = (const char*)Ks[s & 1];
    f32x16 accS0 = {0.f}, accS1 = {0.f};
    __builtin_amdgcn_s_setprio(1);
    #pragma unroll
    for (int kc = 0; kc < 4; kc++) {
      const int row0 = l31;
      const bf16x8 kf0 = *(const bf16x8*)(KsB + row0 * 128 +
                          ((kc*32 + hi*16) ^ ((row0 & 7) << 4)));
      accS0 = __builtin_amdgcn_mfma_f32_32x32x16_bf16(kf0, qf[kc], accS0, 0, 0, 0);
      const int row1 = 32 + l31;
      const bf16x8 kf1 = *(const bf16x8*)(KsB + row1 * 128 +
                          ((kc*32 + hi*16) ^ ((row1 & 7) << 4)));
      accS1 = __builtin_amdgcn_mfma_f32_32x32x16_bf16(kf1, qf[kc], accS1, 0, 0, 0);
    }
    __builtin_amdgcn_s_setprio(0);

    const unsigned va = vbase + (s & 1) * 8192;
    s16x4 vlo[2][4], vhi[2][4];
    #pragma unroll
    for (int dblk = 0; dblk < 2; dblk++) {
      #pragma unroll
      for (int kc = 0; kc < 4; kc++) {
        asm volatile("ds_read_b64_tr_b16 %0, %2 offset:%3\n\t"
                     "ds_read_b64_tr_b16 %1, %2 offset:%4"
                     : "=v"(vlo[dblk][kc]), "=v"(vhi[dblk][kc])
                     : "v"(va), "i"(kc*2048 + dblk*256), "i"(kc*2048 + dblk*256 + 512)
                     : "memory");
      }
    }

    if (tflags[flagBase + kvt] == 0) {
      const size_t mrow = (size_t)(qw0 + l31) * L + kvt * 64;
      #pragma unroll
      for (int r = 0; r < 16; ++r) {
        const int kvr = (r & 3) + 8 * (r >> 2) + 4 * hi;
        if (mask[mrow + kvr] == 0)      accS0[r] = -1e9f;
        if (mask[mrow + 32 + kvr] == 0) accS1[r] = -1e9f;
      }
    }

    #pragma unroll
    for (int r = 0; r < 16; ++r) {
      accS0[r] = __builtin_amdgcn_exp2f(accS0[r]);
      accS1[r] = __builtin_amdgcn_exp2f(accS1[r]);
    }

    union U8 { uint32_t u[4]; bf16x8 v; };
    bf16x8 pa[4];
    #pragma unroll
    for (int b2 = 0; b2 < 2; b2++) {
      const f32x16& P = b2 ? accS1 : accS0;
      uint32_t t0 = cvtpk(P[0], P[1]),  t1 = cvtpk(P[4], P[5]);
      uint32_t u0 = cvtpk(P[2], P[3]),  u1 = cvtpk(P[6], P[7]);
      asm("v_permlane32_swap_b32 %0, %1" : "+v"(t0), "+v"(t1));
      asm("v_permlane32_swap_b32 %0, %1" : "+v"(u0), "+v"(u1));
      U8 f0; f0.u[0] = t0; f0.u[1] = u0; f0.u[2] = t1; f0.u[3] = u1;
      pa[2*b2] = f0.v;
      uint32_t v0 = cvtpk(P[8], P[9]),   v1 = cvtpk(P[12], P[13]);
      uint32_t w0 = cvtpk(P[10], P[11]), w1 = cvtpk(P[14], P[15]);
      asm("v_permlane32_swap_b32 %0, %1" : "+v"(v0), "+v"(v1));
      asm("v_permlane32_swap_b32 %0, %1" : "+v"(w0), "+v"(w1));
      U8 f1; f1.u[0] = v0; f1.u[1] = w0; f1.u[2] = v1; f1.u[3] = w1;
      pa[2*b2+1] = f1.v;
    }

    asm volatile("s_waitcnt lgkmcnt(0)" ::: "memory");
    __builtin_amdgcn_sched_barrier(0);
    __builtin_amdgcn_s_setprio(1);
    #pragma unroll
    for (int kc = 0; kc < 4; kc++) {
      const bf16x8 bv0 = __builtin_shufflevector(vlo[0][kc], vhi[0][kc],
                                                 0, 1, 2, 3, 4, 5, 6, 7);
      accO0 = __builtin_amdgcn_mfma_f32_32x32x16_bf16(pa[kc], bv0, accO0, 0, 0, 0);
      const bf16x8 bv1 = __builtin_shufflevector(vlo[1][kc], vhi[1][kc],
                                                 0, 1, 2, 3, 4, 5, 6, 7);
      accO1 = __builtin_amdgcn_mfma_f32_32x32x16_bf16(pa[kc], bv1, accO1, 0, 0, 0);
      accL  = __builtin_amdgcn_mfma_f32_32x32x16_bf16(pa[kc], onef, accL, 0, 0, 0);
    }
    __builtin_amdgcn_s_setprio(0);
  }

  // ---- epilogue: unnormalized partial O (bf16) + partial l per row
  ushort* Pout = split ? P1 : P0;
  float*  lout = split ? l1 : l0;
  #pragma unroll
  for (int r = 0; r < 16; ++r) {
    const int qr = (r & 3) + 8 * (r >> 2) + 4 * hi;
    const size_t row = (size_t)b * L + qw0 + qr;
    Pout[row * 1024 + h*64 +      l31] = f2bf(accO0[r]);
    Pout[row * 1024 + h*64 + 32 + l31] = f2bf(accO1[r]);
    if (l31 == 0) lout[row * 16 + h] = accL[r];
  }
#undef STAGE
}

// ---------------- combine: AO = (P0 + P1) / (l0 + l1)  (exact under m=0) ------
__global__ __launch_bounds__(256) void combine_kernel(
    const ushort* __restrict__ P0, const ushort* __restrict__ P1,
    const float* __restrict__ l0, const float* __restrict__ l1,
    ushort* __restrict__ AO) {
  const int i = blockIdx.x * 256 + threadIdx.x;   // 8-elem groups, 524288 total
  const int row = i >> 7;
  const int h = (i >> 3) & 15;
  const float inv = 1.0f / (l0[row * 16 + h] + l1[row * 16 + h]);
  const uint4 A = ((const uint4*)P0)[i];
  const uint4 C = ((const uint4*)P1)[i];
  const ushort* ua = (const ushort*)&A;
  const ushort* uc = (const ushort*)&C;
  union { ushort us[8]; uint4 v; } o;
  #pragma unroll
  for (int j = 0; j < 8; j++)
    o.us[j] = f2bf((bf2f(ua[j]) + bf2f(uc[j])) * inv);
  ((uint4*)AO)[i] = o.v;
}

extern "C" void kernel_launch(void* const* d_in, const int* in_sizes, int n_in,
                              void* d_out, int out_size, void* d_ws, size_t ws_size,
                              hipStream_t stream) {
  const float* q    = (const float*)d_in[0];
  const float* k    = (const float*)d_in[1];
  const float* v    = (const float*)d_in[2];
  const int*   mask = (const int*)d_in[3];
  const float* w_q  = (const float*)d_in[4];
  const float* w_k  = (const float*)d_in[5];
  const float* w_v  = (const float*)d_in[6];
  const float* w_o  = (const float*)d_in[7];
  const float* ln_g = (const float*)d_in[8];
  const float* ln_b = (const float*)d_in[9];
  float* out = (float*)d_out;

  char* ws = (char*)d_ws;
  const size_t MB = (size_t)1 << 20;
  ushort* qn  = (ushort*)(ws + 0*MB);    // LN out; reused as P0 after gemm3
  ushort* kb  = (ushort*)(ws + 8*MB);    // k bf16; reused as P1 after gemm3
  ushort* vb  = (ushort*)(ws + 16*MB);   // v bf16; reused for l0/l1/tflags
  ushort* wqb = (ushort*)(ws + 24*MB);
  ushort* wkb = (ushort*)(ws + 26*MB);
  ushort* wvb = (ushort*)(ws + 28*MB);
  ushort* wob = (ushort*)(ws + 30*MB);
  ushort* Qp  = (ushort*)(ws + 32*MB);
  ushort* Kp  = (ushort*)(ws + 40*MB);
  ushort* Vp  = (ushort*)(ws + 48*MB);
  ushort* AO  = (ushort*)(ws + 56*MB);
  ushort* P0  = (ushort*)(ws + 0*MB);
  ushort* P1  = (ushort*)(ws + 8*MB);
  float*  l0  = (float*)(ws + 16*MB);                  // 256 KB
  float*  l1  = (float*)(ws + 16*MB + 256*1024);       // 256 KB
  int* tflags = (int*)(ws + 16*MB + 512*1024);         // 4 KB (vb region, dead)

  const float QSCALE = 0.125f * 1.44269504089f;   // 1/sqrt(64) * log2(e)

  prep_kernel<<<16384, 256, 0, stream>>>(
      q, k, v, w_q, w_k, w_v, w_o, ln_g, ln_b,
      qn, kb, vb, wqb, wkb, wvb, wob);

  gemm3<<<dim3(8, 32, 3), 256, 0, stream>>>(
      qn, wqb, Qp, kb, wkb, Kp, vb, wvb, Vp, QSCALE);

  mask_flags<<<dim3(32, 32), 256, 0, stream>>>(mask, tflags);

  flash_attn<<<dim3(32, 16, 2), 256, 0, stream>>>(
      Qp, Kp, Vp, mask, tflags, P0, P1, l0, l1);

  combine_kernel<<<2048, 256, 0, stream>>>(P0, P1, l0, l1, AO);

  gemm_bm64<<<dim3(8, 64), 256, 0, stream>>>(AO, wob, out, q);
}

// Round 10
// 157.645 us; speedup vs baseline: 1.0438x; 1.0438x over previous
//
#include <hip/hip_runtime.h>
#include <stdint.h>

typedef __attribute__((ext_vector_type(8))) short bf16x8;
typedef __attribute__((ext_vector_type(4))) short s16x4;
typedef __attribute__((ext_vector_type(4))) float f32x4;
typedef __attribute__((ext_vector_type(16))) float f32x16;

__device__ __forceinline__ ushort f2bf(float f) {
  union { float f; uint32_t u; } c; c.f = f;
  uint32_t r = (c.u + 0x7fffu + ((c.u >> 16) & 1u)) >> 16;
  return (ushort)r;
}

__device__ __forceinline__ void gload16(const void* g, void* l) {
  __builtin_amdgcn_global_load_lds(
      (const __attribute__((address_space(1))) void*)g,
      (__attribute__((address_space(3))) void*)l, 16, 0, 0);
}

__device__ __forceinline__ unsigned lds_addr(const void* p) {
  return (unsigned)(uintptr_t)(__attribute__((address_space(3))) const char*)p;
}

__device__ __forceinline__ uint32_t cvtpk(float lo, float hi) {
  uint32_t d;
  asm("v_cvt_pk_bf16_f32 %0, %1, %2" : "=v"(d) : "v"(lo), "v"(hi));
  return d;
}

// ---------------- fused prep: LN(q) + cast k,v + cast 4 weights ----------------
__global__ __launch_bounds__(256) void prep_kernel(
    const float* __restrict__ q, const float* __restrict__ k,
    const float* __restrict__ v, const float* __restrict__ w_q,
    const float* __restrict__ w_k, const float* __restrict__ w_v,
    const float* __restrict__ w_o, const float* __restrict__ ln_g,
    const float* __restrict__ ln_b,
    ushort* __restrict__ qn, ushort* __restrict__ kb, ushort* __restrict__ vb,
    ushort* __restrict__ wqb, ushort* __restrict__ wkb,
    ushort* __restrict__ wvb, ushort* __restrict__ wob) {
  const int bid = blockIdx.x;
  const int t = threadIdx.x;
  if (bid < 4096) {
    const int row = bid;
    const float4 val = ((const float4*)(q + (size_t)row * 1024))[t];
    float s  = val.x + val.y + val.z + val.w;
    float s2 = val.x*val.x + val.y*val.y + val.z*val.z + val.w*val.w;
    #pragma unroll
    for (int off = 1; off < 64; off <<= 1) {
      s  += __shfl_xor(s,  off);
      s2 += __shfl_xor(s2, off);
    }
    __shared__ float red[8];
    const int wave = t >> 6, lane = t & 63;
    if (lane == 0) { red[wave*2] = s; red[wave*2+1] = s2; }
    __syncthreads();
    s  = red[0] + red[2] + red[4] + red[6];
    s2 = red[1] + red[3] + red[5] + red[7];
    const float mu = s * (1.0f/1024.0f);
    const float var = s2 * (1.0f/1024.0f) - mu*mu;
    const float rs = rsqrtf(var + 1e-6f);
    const float4 gg = ((const float4*)ln_g)[t];
    const float4 bb = ((const float4*)ln_b)[t];
    ushort4 o;
    o.x = f2bf((val.x - mu) * rs * gg.x + bb.x);
    o.y = f2bf((val.y - mu) * rs * gg.y + bb.y);
    o.z = f2bf((val.z - mu) * rs * gg.z + bb.z);
    o.w = f2bf((val.w - mu) * rs * gg.w + bb.w);
    ((ushort4*)(qn + (size_t)row * 1024))[t] = o;
    return;
  }
  const float* in; ushort* out; int i;
  if (bid < 12288) {
    const int idx = bid - 4096;
    const bool isv = idx >= 4096;
    in  = isv ? v : k;
    out = isv ? vb : kb;
    i = (idx & 4095) * 256 + t;
  } else {
    const int idx = bid - 12288;
    const int w = idx >> 10;
    in  = w == 0 ? w_q : (w == 1 ? w_k : (w == 2 ? w_v : w_o));
    out = w == 0 ? wqb : (w == 1 ? wkb : (w == 2 ? wvb : wob));
    i = (idx & 1023) * 256 + t;
  }
  const float4 val = ((const float4*)in)[i];
  ushort4 o;
  o.x = f2bf(val.x); o.y = f2bf(val.y); o.z = f2bf(val.z); o.w = f2bf(val.w);
  ((ushort4*)out)[i] = o;
}

// ---------------- mask tile flags (64x64 granularity) ----------------
__global__ __launch_bounds__(256) void mask_flags(
    const int* __restrict__ mask, int* __restrict__ flags) {
  const int qt = blockIdx.y, kt = blockIdx.x;
  const int t = threadIdx.x;
  const int* p = mask + (size_t)(qt * 64 + (t >> 2)) * 2048 + kt * 64 + (t & 3) * 16;
  int ok = 1;
  #pragma unroll
  for (int i = 0; i < 4; i++) {
    const int4 m = ((const int4*)p)[i];
    ok &= (m.x != 0) & (m.y != 0) & (m.z != 0) & (m.w != 0);
  }
  __shared__ int sok;
  if (t == 0) sok = 1;
  __syncthreads();
  if (!ok) atomicAnd(&sok, 0);
  __syncthreads();
  if (t == 0) flags[qt * 32 + kt] = sok;
}

// ---------------- QKV GEMM (R4-proven 4-buffer pipeline) ----------------
__global__ __launch_bounds__(256) void gemm3(
    const ushort* __restrict__ A0, const ushort* __restrict__ W0, ushort* __restrict__ C0,
    const ushort* __restrict__ A1, const ushort* __restrict__ W1, ushort* __restrict__ C1,
    const ushort* __restrict__ A2, const ushort* __restrict__ W2, ushort* __restrict__ C2,
    float qscale) {
  __shared__ ushort As[4][4096];
  __shared__ ushort Bs[4][4096];
  const int t = threadIdx.x, lane = t & 63, wave = t >> 6;
  const int wr = wave >> 1, wc = wave & 1;
  const int lr = lane & 15, lg = lane >> 4;
  const int brow = blockIdx.y * 128, bcol = blockIdx.x * 128;
  const int z = blockIdx.z;
  const ushort* A = z == 0 ? A0 : (z == 1 ? A1 : A2);
  const ushort* W = z == 0 ? W0 : (z == 1 ? W1 : W2);
  ushort*      C = z == 0 ? C0 : (z == 1 ? C1 : C2);
  const float sc = (z == 0) ? qscale : 1.0f;
  f32x4 acc[4][4] = {};
  const ushort* gA = A + (size_t)(brow + (t >> 2)) * 1024 + (t & 3) * 8;
  const ushort* gB = W + (size_t)(bcol + (t >> 2)) * 1024 + (t & 3) * 8;
  const int woff = wave * 1024;

#define G_ISSUE(S) { \
    char* la = (char*)As + ((S) & 3) * 8192 + woff; \
    char* lb = (char*)Bs + ((S) & 3) * 8192 + woff; \
    const ushort* ap_ = gA + (S) * 32; \
    const ushort* bp_ = gB + (S) * 32; \
    gload16(ap_, la); gload16(ap_ + 64 * 1024, la + 4096); \
    gload16(bp_, lb); gload16(bp_ + 64 * 1024, lb + 4096); }

#define G_COMPUTE(S) { \
    const ushort* as_ = As[(S) & 3]; \
    const ushort* bs_ = Bs[(S) & 3]; \
    bf16x8 af[4], bfr[4]; \
    _Pragma("unroll") for (int i = 0; i < 4; i++) \
      af[i]  = *(const bf16x8*)&as_[(wr*64 + i*16 + lr) * 32 + lg*8]; \
    _Pragma("unroll") for (int i = 0; i < 4; i++) \
      bfr[i] = *(const bf16x8*)&bs_[(wc*64 + i*16 + lr) * 32 + lg*8]; \
    _Pragma("unroll") for (int mi = 0; mi < 4; mi++) \
      _Pragma("unroll") for (int ni = 0; ni < 4; ni++) \
        acc[mi][ni] = __builtin_amdgcn_mfma_f32_16x16x32_bf16(af[mi], bfr[ni], acc[mi][ni], 0, 0, 0); }

  G_ISSUE(0); G_ISSUE(1); G_ISSUE(2);
  for (int s = 0; s < 30; ++s) {
    asm volatile("s_waitcnt vmcnt(8)" ::: "memory");
    __builtin_amdgcn_s_barrier();
    if (s < 29) G_ISSUE(s + 3);
    G_COMPUTE(s);
  }
  asm volatile("s_waitcnt vmcnt(4)" ::: "memory");
  __builtin_amdgcn_s_barrier();
  G_COMPUTE(30);
  asm volatile("s_waitcnt vmcnt(0)" ::: "memory");
  __builtin_amdgcn_s_barrier();
  G_COMPUTE(31);
#undef G_ISSUE
#undef G_COMPUTE

  #pragma unroll
  for (int mi = 0; mi < 4; mi++) {
    #pragma unroll
    for (int ni = 0; ni < 4; ni++) {
      #pragma unroll
      for (int r = 0; r < 4; r++) {
        const size_t row = brow + wr*64 + mi*16 + lg*4 + r;
        const size_t col = bcol + wc*64 + ni*16 + lr;
        C[row * 1024 + col] = f2bf(acc[mi][ni][r] * sc);
      }
    }
  }
}

// ---------------- Final GEMM: BM=64, fused residual (R8-proven) ----------------
__global__ __launch_bounds__(256) void gemm_bm64(
    const ushort* __restrict__ A, const ushort* __restrict__ W,
    float* __restrict__ Cf, const float* __restrict__ resid) {
  __shared__ ushort As[4][2048];
  __shared__ ushort Bs[4][4096];
  const int t = threadIdx.x, lane = t & 63, wave = t >> 6;
  const int wr = wave >> 1, wc = wave & 1;
  const int lr = lane & 15, lg = lane >> 4;
  const int brow = blockIdx.y * 64, bcol = blockIdx.x * 128;
  f32x4 acc[2][4] = {};
  const ushort* gA = A + (size_t)(brow + (t >> 2)) * 1024 + (t & 3) * 8;
  const ushort* gB = W + (size_t)(bcol + (t >> 2)) * 1024 + (t & 3) * 8;
  const int woff = wave * 1024;

#define G_ISSUE(S) { \
    char* la = (char*)As + ((S) & 3) * 4096 + woff; \
    char* lb = (char*)Bs + ((S) & 3) * 8192 + woff; \
    const ushort* ap_ = gA + (S) * 32; \
    const ushort* bp_ = gB + (S) * 32; \
    gload16(ap_, la); \
    gload16(bp_, lb); gload16(bp_ + 64 * 1024, lb + 4096); }

#define G_COMPUTE(S) { \
    const ushort* as_ = As[(S) & 3]; \
    const ushort* bs_ = Bs[(S) & 3]; \
    bf16x8 af[2], bfr[4]; \
    _Pragma("unroll") for (int i = 0; i < 2; i++) \
      af[i]  = *(const bf16x8*)&as_[(wr*32 + i*16 + lr) * 32 + lg*8]; \
    _Pragma("unroll") for (int i = 0; i < 4; i++) \
      bfr[i] = *(const bf16x8*)&bs_[(wc*64 + i*16 + lr) * 32 + lg*8]; \
    _Pragma("unroll") for (int mi = 0; mi < 2; mi++) \
      _Pragma("unroll") for (int ni = 0; ni < 4; ni++) \
        acc[mi][ni] = __builtin_amdgcn_mfma_f32_16x16x32_bf16(af[mi], bfr[ni], acc[mi][ni], 0, 0, 0); }

  G_ISSUE(0); G_ISSUE(1); G_ISSUE(2);
  for (int s = 0; s < 30; ++s) {
    asm volatile("s_waitcnt vmcnt(6)" ::: "memory");
    __builtin_amdgcn_s_barrier();
    if (s < 29) G_ISSUE(s + 3);
    G_COMPUTE(s);
  }
  asm volatile("s_waitcnt vmcnt(3)" ::: "memory");
  __builtin_amdgcn_s_barrier();
  G_COMPUTE(30);
  asm volatile("s_waitcnt vmcnt(0)" ::: "memory");
  __builtin_amdgcn_s_barrier();
  G_COMPUTE(31);
#undef G_ISSUE
#undef G_COMPUTE

  #pragma unroll
  for (int mi = 0; mi < 2; mi++) {
    #pragma unroll
    for (int ni = 0; ni < 4; ni++) {
      #pragma unroll
      for (int r = 0; r < 4; r++) {
        const size_t row = brow + wr*32 + mi*16 + lg*4 + r;
        const size_t col = bcol + wc*64 + ni*16 + lr;
        Cf[row * 1024 + col] = acc[mi][ni][r] + resid[row * 1024 + col];
      }
    }
  }
}

// ---------------- Flash attention: R7 body, PAIRED tiles (1 sync per 128 kv) ---
// K/V: 2 pair-buffers of 16KB each (tile-even at +0, tile-odd at +8192); 64KB LDS.
// Residency is register-capped at 2 blocks/CU, so the LDS is free capacity.
// m=0 softmax (exact: Q pre-scaled, scores O(1)); l via MFMA(P, ones).
__global__ __launch_bounds__(256) void flash_attn(
    const ushort* __restrict__ Qp, const ushort* __restrict__ Kp,
    const ushort* __restrict__ Vp, const int* __restrict__ mask,
    const int* __restrict__ tflags, ushort* __restrict__ AO) {
  const int L = 2048;
  const int qb = blockIdx.x, h = blockIdx.y, b = blockIdx.z;
  const int t = threadIdx.x, lane = t & 63, wave = t >> 6;
  const int l31 = lane & 31, hi = lane >> 5;
  __shared__ ushort Ks[2][8192];   // pair buffer: 2 tiles x 8KB
  __shared__ ushort Vs[2][8192];
  const size_t base = (size_t)b * L * 1024 + h * 64;
  const int qw0 = qb * 128 + wave * 32;

  bf16x8 qf[4];
  #pragma unroll
  for (int kc = 0; kc < 4; kc++)
    qf[kc] = *(const bf16x8*)(Qp + base + (size_t)(qw0 + l31) * 1024 + kc*16 + hi*8);

  f32x16 accO0 = {0.f}, accO1 = {0.f}, accL = {0.f};
  const bf16x8 onef = {16256, 16256, 16256, 16256, 16256, 16256, 16256, 16256};

  const int r3 = (lane >> 3) & 7;
  const int c3 = (lane & 7) ^ r3;
  const ushort* gK = Kp + base + (size_t)(wave*8 + r3) * 1024 + c3 * 8;
  const int sv = t >> 3, hv = t & 7;
  const int vkv = (sv >> 2) * 4 + (hv >> 1);
  const int vd  = (sv & 3) * 16 + (hv & 1) * 8;
  const ushort* gV = Vp + base + (size_t)vkv * 1024 + vd;

  const unsigned vbase = lds_addr((const char*)Vs) + hi * 1024 +
                         ((lane >> 4) & 1) * 128 + (lane & 15) * 8;

  // stage BOTH tiles of pair P into pair-buffer BUF (8 gloads/wave)
#define STAGE2(P, BUF) { \
    char* kb_ = (char*)Ks[BUF] + wave * 1024; \
    const ushort* gk_ = gK + (size_t)(2*(P)) * 65536; \
    gload16(gk_,             kb_);         gload16(gk_ + 32*1024, kb_ + 4096); \
    gload16(gk_ + 64*1024,   kb_ + 8192);  gload16(gk_ + 96*1024, kb_ + 12288); \
    char* vb_ = (char*)Vs[BUF] + wave * 1024; \
    const ushort* gv_ = gV + (size_t)(2*(P)) * 65536; \
    gload16(gv_,             vb_);         gload16(gv_ + 32*1024, vb_ + 4096); \
    gload16(gv_ + 64*1024,   vb_ + 8192);  gload16(gv_ + 96*1024, vb_ + 12288); }

  STAGE2(0, 0);
  const int flagBase = (qb * 2 + (wave >> 1)) * 32;

  for (int p = 0; p < 16; ++p) {
    asm volatile("s_waitcnt vmcnt(0)" ::: "memory");
    __builtin_amdgcn_s_barrier();
    if (p + 1 < 16) { STAGE2(p + 1, (p + 1) & 1); }

    #pragma unroll
    for (int half = 0; half < 2; ++half) {
      const int kvt = 2*p + half;
      const char* KsB = (const char*)Ks[p & 1] + half * 8192;
      f32x16 accS0 = {0.f}, accS1 = {0.f};
      __builtin_amdgcn_s_setprio(1);
      #pragma unroll
      for (int kc = 0; kc < 4; kc++) {
        const int row0 = l31;
        const bf16x8 kf0 = *(const bf16x8*)(KsB + row0 * 128 +
                            ((kc*32 + hi*16) ^ ((row0 & 7) << 4)));
        accS0 = __builtin_amdgcn_mfma_f32_32x32x16_bf16(kf0, qf[kc], accS0, 0, 0, 0);
        const int row1 = 32 + l31;
        const bf16x8 kf1 = *(const bf16x8*)(KsB + row1 * 128 +
                            ((kc*32 + hi*16) ^ ((row1 & 7) << 4)));
        accS1 = __builtin_amdgcn_mfma_f32_32x32x16_bf16(kf1, qf[kc], accS1, 0, 0, 0);
      }
      __builtin_amdgcn_s_setprio(0);

      const unsigned va = vbase + (p & 1) * 16384 + half * 8192;
      s16x4 vlo[2][4], vhi[2][4];
      #pragma unroll
      for (int dblk = 0; dblk < 2; dblk++) {
        #pragma unroll
        for (int kc = 0; kc < 4; kc++) {
          asm volatile("ds_read_b64_tr_b16 %0, %2 offset:%3\n\t"
                       "ds_read_b64_tr_b16 %1, %2 offset:%4"
                       : "=v"(vlo[dblk][kc]), "=v"(vhi[dblk][kc])
                       : "v"(va), "i"(kc*2048 + dblk*256), "i"(kc*2048 + dblk*256 + 512)
                       : "memory");
        }
      }

      if (tflags[flagBase + kvt] == 0) {
        const size_t mrow = (size_t)(qw0 + l31) * L + kvt * 64;
        #pragma unroll
        for (int r = 0; r < 16; ++r) {
          const int kvr = (r & 3) + 8 * (r >> 2) + 4 * hi;
          if (mask[mrow + kvr] == 0)      accS0[r] = -1e9f;
          if (mask[mrow + 32 + kvr] == 0) accS1[r] = -1e9f;
        }
      }

      #pragma unroll
      for (int r = 0; r < 16; ++r) {
        accS0[r] = __builtin_amdgcn_exp2f(accS0[r]);
        accS1[r] = __builtin_amdgcn_exp2f(accS1[r]);
      }

      union U8 { uint32_t u[4]; bf16x8 v; };
      bf16x8 pa[4];
      #pragma unroll
      for (int b2 = 0; b2 < 2; b2++) {
        const f32x16& P = b2 ? accS1 : accS0;
        uint32_t t0 = cvtpk(P[0], P[1]),  t1 = cvtpk(P[4], P[5]);
        uint32_t u0 = cvtpk(P[2], P[3]),  u1 = cvtpk(P[6], P[7]);
        asm("v_permlane32_swap_b32 %0, %1" : "+v"(t0), "+v"(t1));
        asm("v_permlane32_swap_b32 %0, %1" : "+v"(u0), "+v"(u1));
        U8 f0; f0.u[0] = t0; f0.u[1] = u0; f0.u[2] = t1; f0.u[3] = u1;
        pa[2*b2] = f0.v;
        uint32_t v0 = cvtpk(P[8], P[9]),   v1 = cvtpk(P[12], P[13]);
        uint32_t w0 = cvtpk(P[10], P[11]), w1 = cvtpk(P[14], P[15]);
        asm("v_permlane32_swap_b32 %0, %1" : "+v"(v0), "+v"(v1));
        asm("v_permlane32_swap_b32 %0, %1" : "+v"(w0), "+v"(w1));
        U8 f1; f1.u[0] = v0; f1.u[1] = w0; f1.u[2] = v1; f1.u[3] = w1;
        pa[2*b2+1] = f1.v;
      }

      asm volatile("s_waitcnt lgkmcnt(0)" ::: "memory");
      __builtin_amdgcn_sched_barrier(0);
      __builtin_amdgcn_s_setprio(1);
      #pragma unroll
      for (int kc = 0; kc < 4; kc++) {
        const bf16x8 bv0 = __builtin_shufflevector(vlo[0][kc], vhi[0][kc],
                                                   0, 1, 2, 3, 4, 5, 6, 7);
        accO0 = __builtin_amdgcn_mfma_f32_32x32x16_bf16(pa[kc], bv0, accO0, 0, 0, 0);
        const bf16x8 bv1 = __builtin_shufflevector(vlo[1][kc], vhi[1][kc],
                                                   0, 1, 2, 3, 4, 5, 6, 7);
        accO1 = __builtin_amdgcn_mfma_f32_32x32x16_bf16(pa[kc], bv1, accO1, 0, 0, 0);
        accL  = __builtin_amdgcn_mfma_f32_32x32x16_bf16(pa[kc], onef, accL, 0, 0, 0);
      }
      __builtin_amdgcn_s_setprio(0);
    }
  }

  #pragma unroll
  for (int r = 0; r < 16; ++r) {
    const int qr = (r & 3) + 8 * (r >> 2) + 4 * hi;
    const float inv = 1.0f / accL[r];
    const size_t row = (size_t)b * L + qw0 + qr;
    AO[row * 1024 + h*64 +      l31] = f2bf(accO0[r] * inv);
    AO[row * 1024 + h*64 + 32 + l31] = f2bf(accO1[r] * inv);
  }
#undef STAGE2
}

extern "C" void kernel_launch(void* const* d_in, const int* in_sizes, int n_in,
                              void* d_out, int out_size, void* d_ws, size_t ws_size,
                              hipStream_t stream) {
  const float* q    = (const float*)d_in[0];
  const float* k    = (const float*)d_in[1];
  const float* v    = (const float*)d_in[2];
  const int*   mask = (const int*)d_in[3];
  const float* w_q  = (const float*)d_in[4];
  const float* w_k  = (const float*)d_in[5];
  const float* w_v  = (const float*)d_in[6];
  const float* w_o  = (const float*)d_in[7];
  const float* ln_g = (const float*)d_in[8];
  const float* ln_b = (const float*)d_in[9];
  float* out = (float*)d_out;

  char* ws = (char*)d_ws;
  const size_t MB = (size_t)1 << 20;
  ushort* qn  = (ushort*)(ws + 0*MB);
  ushort* kb  = (ushort*)(ws + 8*MB);    // dead after QKV GEMM; tflags reuses it
  ushort* vb  = (ushort*)(ws + 16*MB);
  ushort* wqb = (ushort*)(ws + 24*MB);
  ushort* wkb = (ushort*)(ws + 26*MB);
  ushort* wvb = (ushort*)(ws + 28*MB);
  ushort* wob = (ushort*)(ws + 30*MB);
  ushort* Qp  = (ushort*)(ws + 32*MB);
  ushort* Kp  = (ushort*)(ws + 40*MB);
  ushort* Vp  = (ushort*)(ws + 48*MB);
  ushort* AO  = (ushort*)(ws + 56*MB);
  int* tflags = (int*)(ws + 8*MB);       // written after gemm3 consumed kb

  const float QSCALE = 0.125f * 1.44269504089f;   // 1/sqrt(64) * log2(e)

  prep_kernel<<<16384, 256, 0, stream>>>(
      q, k, v, w_q, w_k, w_v, w_o, ln_g, ln_b,
      qn, kb, vb, wqb, wkb, wvb, wob);

  gemm3<<<dim3(8, 32, 3), 256, 0, stream>>>(
      qn, wqb, Qp, kb, wkb, Kp, vb, wvb, Vp, QSCALE);

  mask_flags<<<dim3(32, 32), 256, 0, stream>>>(mask, tflags);

  flash_attn<<<dim3(16, 16, 2), 256, 0, stream>>>(Qp, Kp, Vp, mask, tflags, AO);

  gemm_bm64<<<dim3(8, 64), 256, 0, stream>>>(AO, wob, out, q);
}

// Round 11
// 145.065 us; speedup vs baseline: 1.1344x; 1.0867x over previous
//
#include <hip/hip_runtime.h>
#include <stdint.h>

typedef __attribute__((ext_vector_type(8))) short bf16x8;
typedef __attribute__((ext_vector_type(4))) short s16x4;
typedef __attribute__((ext_vector_type(4))) float f32x4;
typedef __attribute__((ext_vector_type(16))) float f32x16;

__device__ __forceinline__ ushort f2bf(float f) {
  union { float f; uint32_t u; } c; c.f = f;
  uint32_t r = (c.u + 0x7fffu + ((c.u >> 16) & 1u)) >> 16;
  return (ushort)r;
}

__device__ __forceinline__ void gload16(const void* g, void* l) {
  __builtin_amdgcn_global_load_lds(
      (const __attribute__((address_space(1))) void*)g,
      (__attribute__((address_space(3))) void*)l, 16, 0, 0);
}

__device__ __forceinline__ unsigned lds_addr(const void* p) {
  return (unsigned)(uintptr_t)(__attribute__((address_space(3))) const char*)p;
}

__device__ __forceinline__ uint32_t cvtpk(float lo, float hi) {
  uint32_t d;
  asm("v_cvt_pk_bf16_f32 %0, %1, %2" : "=v"(d) : "v"(lo), "v"(hi));
  return d;
}

// ---------------- fused prep: LN(q) + cast k,v + cast 4 weights ----------------
__global__ __launch_bounds__(256) void prep_kernel(
    const float* __restrict__ q, const float* __restrict__ k,
    const float* __restrict__ v, const float* __restrict__ w_q,
    const float* __restrict__ w_k, const float* __restrict__ w_v,
    const float* __restrict__ w_o, const float* __restrict__ ln_g,
    const float* __restrict__ ln_b,
    ushort* __restrict__ qn, ushort* __restrict__ kb, ushort* __restrict__ vb,
    ushort* __restrict__ wqb, ushort* __restrict__ wkb,
    ushort* __restrict__ wvb, ushort* __restrict__ wob) {
  const int bid = blockIdx.x;
  const int t = threadIdx.x;
  if (bid < 4096) {
    const int row = bid;
    const float4 val = ((const float4*)(q + (size_t)row * 1024))[t];
    float s  = val.x + val.y + val.z + val.w;
    float s2 = val.x*val.x + val.y*val.y + val.z*val.z + val.w*val.w;
    #pragma unroll
    for (int off = 1; off < 64; off <<= 1) {
      s  += __shfl_xor(s,  off);
      s2 += __shfl_xor(s2, off);
    }
    __shared__ float red[8];
    const int wave = t >> 6, lane = t & 63;
    if (lane == 0) { red[wave*2] = s; red[wave*2+1] = s2; }
    __syncthreads();
    s  = red[0] + red[2] + red[4] + red[6];
    s2 = red[1] + red[3] + red[5] + red[7];
    const float mu = s * (1.0f/1024.0f);
    const float var = s2 * (1.0f/1024.0f) - mu*mu;
    const float rs = rsqrtf(var + 1e-6f);
    const float4 gg = ((const float4*)ln_g)[t];
    const float4 bb = ((const float4*)ln_b)[t];
    ushort4 o;
    o.x = f2bf((val.x - mu) * rs * gg.x + bb.x);
    o.y = f2bf((val.y - mu) * rs * gg.y + bb.y);
    o.z = f2bf((val.z - mu) * rs * gg.z + bb.z);
    o.w = f2bf((val.w - mu) * rs * gg.w + bb.w);
    ((ushort4*)(qn + (size_t)row * 1024))[t] = o;
    return;
  }
  const float* in; ushort* out; int i;
  if (bid < 12288) {
    const int idx = bid - 4096;
    const bool isv = idx >= 4096;
    in  = isv ? v : k;
    out = isv ? vb : kb;
    i = (idx & 4095) * 256 + t;
  } else {
    const int idx = bid - 12288;
    const int w = idx >> 10;
    in  = w == 0 ? w_q : (w == 1 ? w_k : (w == 2 ? w_v : w_o));
    out = w == 0 ? wqb : (w == 1 ? wkb : (w == 2 ? wvb : wob));
    i = (idx & 1023) * 256 + t;
  }
  const float4 val = ((const float4*)in)[i];
  ushort4 o;
  o.x = f2bf(val.x); o.y = f2bf(val.y); o.z = f2bf(val.z); o.w = f2bf(val.w);
  ((ushort4*)out)[i] = o;
}

// ---------------- mask tile flags (64x64 granularity) ----------------
__global__ __launch_bounds__(256) void mask_flags(
    const int* __restrict__ mask, int* __restrict__ flags) {
  const int qt = blockIdx.y, kt = blockIdx.x;
  const int t = threadIdx.x;
  const int* p = mask + (size_t)(qt * 64 + (t >> 2)) * 2048 + kt * 64 + (t & 3) * 16;
  int ok = 1;
  #pragma unroll
  for (int i = 0; i < 4; i++) {
    const int4 m = ((const int4*)p)[i];
    ok &= (m.x != 0) & (m.y != 0) & (m.z != 0) & (m.w != 0);
  }
  __shared__ int sok;
  if (t == 0) sok = 1;
  __syncthreads();
  if (!ok) atomicAnd(&sok, 0);
  __syncthreads();
  if (t == 0) flags[qt * 32 + kt] = sok;
}

// ---------------- QKV GEMM: XCD-swizzled grid + T2 LDS XOR-swizzle -------------
// R4-proven 4-buffer vmcnt(8) pipeline. 1-D grid 768 = 8 XCD chunks x 96.
// LDS: chunk c of row r stored at linear pos c, CONTENT is global chunk
// c ^ ((r>>1)&3) (source pre-swizzle); read at lg ^ ((lr>>1)&3) -> 2-way banks.
__global__ __launch_bounds__(256) void gemm3(
    const ushort* __restrict__ A0, const ushort* __restrict__ W0, ushort* __restrict__ C0,
    const ushort* __restrict__ A1, const ushort* __restrict__ W1, ushort* __restrict__ C1,
    const ushort* __restrict__ A2, const ushort* __restrict__ W2, ushort* __restrict__ C2,
    float qscale) {
  __shared__ ushort As[4][4096];
  __shared__ ushort Bs[4][4096];
  const int t = threadIdx.x, lane = t & 63, wave = t >> 6;
  const int wr = wave >> 1, wc = wave & 1;
  const int lr = lane & 15, lg = lane >> 4;
  const int lin = blockIdx.x;
  const int swz = (lin & 7) * 96 + (lin >> 3);     // bijective: 768 = 8*96
  const int brow = ((swz >> 3) & 31) * 128, bcol = (swz & 7) * 128;
  const int z = swz >> 8;
  const ushort* A = z == 0 ? A0 : (z == 1 ? A1 : A2);
  const ushort* W = z == 0 ? W0 : (z == 1 ? W1 : W2);
  ushort*      C = z == 0 ? C0 : (z == 1 ? C1 : C2);
  const float sc = (z == 0) ? qscale : 1.0f;
  f32x4 acc[4][4] = {};
  const int r_ = t >> 2, cx = (t & 3) ^ ((r_ >> 1) & 3);   // source chunk XOR
  const ushort* gA = A + (size_t)(brow + r_) * 1024 + cx * 8;
  const ushort* gB = W + (size_t)(bcol + r_) * 1024 + cx * 8;
  const int woff = wave * 1024;
  const int xA = ((lr >> 1) & 3) * 8;                      // read-side XOR (ushorts)

#define G_ISSUE(S) { \
    char* la = (char*)As + ((S) & 3) * 8192 + woff; \
    char* lb = (char*)Bs + ((S) & 3) * 8192 + woff; \
    const ushort* ap_ = gA + (S) * 32; \
    const ushort* bp_ = gB + (S) * 32; \
    gload16(ap_, la); gload16(ap_ + 64 * 1024, la + 4096); \
    gload16(bp_, lb); gload16(bp_ + 64 * 1024, lb + 4096); }

#define G_COMPUTE(S) { \
    const ushort* as_ = As[(S) & 3]; \
    const ushort* bs_ = Bs[(S) & 3]; \
    bf16x8 af[4], bfr[4]; \
    _Pragma("unroll") for (int i = 0; i < 4; i++) \
      af[i]  = *(const bf16x8*)&as_[(wr*64 + i*16 + lr) * 32 + ((lg*8) ^ xA)]; \
    _Pragma("unroll") for (int i = 0; i < 4; i++) \
      bfr[i] = *(const bf16x8*)&bs_[(wc*64 + i*16 + lr) * 32 + ((lg*8) ^ xA)]; \
    _Pragma("unroll") for (int mi = 0; mi < 4; mi++) \
      _Pragma("unroll") for (int ni = 0; ni < 4; ni++) \
        acc[mi][ni] = __builtin_amdgcn_mfma_f32_16x16x32_bf16(af[mi], bfr[ni], acc[mi][ni], 0, 0, 0); }

  G_ISSUE(0); G_ISSUE(1); G_ISSUE(2);
  for (int s = 0; s < 30; ++s) {
    asm volatile("s_waitcnt vmcnt(8)" ::: "memory");
    __builtin_amdgcn_s_barrier();
    if (s < 29) G_ISSUE(s + 3);
    G_COMPUTE(s);
  }
  asm volatile("s_waitcnt vmcnt(4)" ::: "memory");
  __builtin_amdgcn_s_barrier();
  G_COMPUTE(30);
  asm volatile("s_waitcnt vmcnt(0)" ::: "memory");
  __builtin_amdgcn_s_barrier();
  G_COMPUTE(31);
#undef G_ISSUE
#undef G_COMPUTE

  #pragma unroll
  for (int mi = 0; mi < 4; mi++) {
    #pragma unroll
    for (int ni = 0; ni < 4; ni++) {
      #pragma unroll
      for (int r = 0; r < 4; r++) {
        const size_t row = brow + wr*64 + mi*16 + lg*4 + r;
        const size_t col = bcol + wc*64 + ni*16 + lr;
        C[row * 1024 + col] = f2bf(acc[mi][ni][r] * sc);
      }
    }
  }
}

// ---------------- Final GEMM: BM=64, XCD+T2 swizzles, fused residual -----------
__global__ __launch_bounds__(256) void gemm_bm64(
    const ushort* __restrict__ A, const ushort* __restrict__ W,
    float* __restrict__ Cf, const float* __restrict__ resid) {
  __shared__ ushort As[4][2048];
  __shared__ ushort Bs[4][4096];
  const int t = threadIdx.x, lane = t & 63, wave = t >> 6;
  const int wr = wave >> 1, wc = wave & 1;
  const int lr = lane & 15, lg = lane >> 4;
  const int lin = blockIdx.x;
  const int swz = (lin & 7) * 64 + (lin >> 3);     // bijective: 512 = 8*64
  const int brow = (swz >> 3) * 64, bcol = (swz & 7) * 128;
  f32x4 acc[2][4] = {};
  const int r_ = t >> 2, cx = (t & 3) ^ ((r_ >> 1) & 3);
  const ushort* gA = A + (size_t)(brow + r_) * 1024 + cx * 8;
  const ushort* gB = W + (size_t)(bcol + r_) * 1024 + cx * 8;
  const int woff = wave * 1024;
  const int xA = ((lr >> 1) & 3) * 8;

#define G_ISSUE(S) { \
    char* la = (char*)As + ((S) & 3) * 4096 + woff; \
    char* lb = (char*)Bs + ((S) & 3) * 8192 + woff; \
    const ushort* ap_ = gA + (S) * 32; \
    const ushort* bp_ = gB + (S) * 32; \
    gload16(ap_, la); \
    gload16(bp_, lb); gload16(bp_ + 64 * 1024, lb + 4096); }

#define G_COMPUTE(S) { \
    const ushort* as_ = As[(S) & 3]; \
    const ushort* bs_ = Bs[(S) & 3]; \
    bf16x8 af[2], bfr[4]; \
    _Pragma("unroll") for (int i = 0; i < 2; i++) \
      af[i]  = *(const bf16x8*)&as_[(wr*32 + i*16 + lr) * 32 + ((lg*8) ^ xA)]; \
    _Pragma("unroll") for (int i = 0; i < 4; i++) \
      bfr[i] = *(const bf16x8*)&bs_[(wc*64 + i*16 + lr) * 32 + ((lg*8) ^ xA)]; \
    _Pragma("unroll") for (int mi = 0; mi < 2; mi++) \
      _Pragma("unroll") for (int ni = 0; ni < 4; ni++) \
        acc[mi][ni] = __builtin_amdgcn_mfma_f32_16x16x32_bf16(af[mi], bfr[ni], acc[mi][ni], 0, 0, 0); }

  G_ISSUE(0); G_ISSUE(1); G_ISSUE(2);
  for (int s = 0; s < 30; ++s) {
    asm volatile("s_waitcnt vmcnt(6)" ::: "memory");
    __builtin_amdgcn_s_barrier();
    if (s < 29) G_ISSUE(s + 3);
    G_COMPUTE(s);
  }
  asm volatile("s_waitcnt vmcnt(3)" ::: "memory");
  __builtin_amdgcn_s_barrier();
  G_COMPUTE(30);
  asm volatile("s_waitcnt vmcnt(0)" ::: "memory");
  __builtin_amdgcn_s_barrier();
  G_COMPUTE(31);
#undef G_ISSUE
#undef G_COMPUTE

  #pragma unroll
  for (int mi = 0; mi < 2; mi++) {
    #pragma unroll
    for (int ni = 0; ni < 4; ni++) {
      #pragma unroll
      for (int r = 0; r < 4; r++) {
        const size_t row = brow + wr*32 + mi*16 + lg*4 + r;
        const size_t col = bcol + wc*64 + ni*16 + lr;
        Cf[row * 1024 + col] = acc[mi][ni][r] + resid[row * 1024 + col];
      }
    }
  }
}

// ---------------- Flash attention: R10-proven paired-tile body + XCD swizzle ---
__global__ __launch_bounds__(256) void flash_attn(
    const ushort* __restrict__ Qp, const ushort* __restrict__ Kp,
    const ushort* __restrict__ Vp, const int* __restrict__ mask,
    const int* __restrict__ tflags, ushort* __restrict__ AO) {
  const int L = 2048;
  const int lin = blockIdx.x;
  const int swzb = (lin & 7) * 64 + (lin >> 3);    // bijective: 512 = 8*64
  const int qb = swzb & 15, h = (swzb >> 4) & 15, b = swzb >> 8;
  const int t = threadIdx.x, lane = t & 63, wave = t >> 6;
  const int l31 = lane & 31, hi = lane >> 5;
  __shared__ ushort Ks[2][8192];   // pair buffer: 2 tiles x 8KB
  __shared__ ushort Vs[2][8192];
  const size_t base = (size_t)b * L * 1024 + h * 64;
  const int qw0 = qb * 128 + wave * 32;

  bf16x8 qf[4];
  #pragma unroll
  for (int kc = 0; kc < 4; kc++)
    qf[kc] = *(const bf16x8*)(Qp + base + (size_t)(qw0 + l31) * 1024 + kc*16 + hi*8);

  f32x16 accO0 = {0.f}, accO1 = {0.f}, accL = {0.f};
  const bf16x8 onef = {16256, 16256, 16256, 16256, 16256, 16256, 16256, 16256};

  const int r3 = (lane >> 3) & 7;
  const int c3 = (lane & 7) ^ r3;
  const ushort* gK = Kp + base + (size_t)(wave*8 + r3) * 1024 + c3 * 8;
  const int sv = t >> 3, hv = t & 7;
  const int vkv = (sv >> 2) * 4 + (hv >> 1);
  const int vd  = (sv & 3) * 16 + (hv & 1) * 8;
  const ushort* gV = Vp + base + (size_t)vkv * 1024 + vd;

  const unsigned vbase = lds_addr((const char*)Vs) + hi * 1024 +
                         ((lane >> 4) & 1) * 128 + (lane & 15) * 8;

#define STAGE2(P, BUF) { \
    char* kb_ = (char*)Ks[BUF] + wave * 1024; \
    const ushort* gk_ = gK + (size_t)(2*(P)) * 65536; \
    gload16(gk_,             kb_);         gload16(gk_ + 32*1024, kb_ + 4096); \
    gload16(gk_ + 64*1024,   kb_ + 8192);  gload16(gk_ + 96*1024, kb_ + 12288); \
    char* vb_ = (char*)Vs[BUF] + wave * 1024; \
    const ushort* gv_ = gV + (size_t)(2*(P)) * 65536; \
    gload16(gv_,             vb_);         gload16(gv_ + 32*1024, vb_ + 4096); \
    gload16(gv_ + 64*1024,   vb_ + 8192);  gload16(gv_ + 96*1024, vb_ + 12288); }

  STAGE2(0, 0);
  const int flagBase = (qb * 2 + (wave >> 1)) * 32;

  for (int p = 0; p < 16; ++p) {
    asm volatile("s_waitcnt vmcnt(0)" ::: "memory");
    __builtin_amdgcn_s_barrier();
    if (p + 1 < 16) { STAGE2(p + 1, (p + 1) & 1); }

    #pragma unroll
    for (int half = 0; half < 2; ++half) {
      const int kvt = 2*p + half;
      const char* KsB = (const char*)Ks[p & 1] + half * 8192;
      f32x16 accS0 = {0.f}, accS1 = {0.f};
      __builtin_amdgcn_s_setprio(1);
      #pragma unroll
      for (int kc = 0; kc < 4; kc++) {
        const int row0 = l31;
        const bf16x8 kf0 = *(const bf16x8*)(KsB + row0 * 128 +
                            ((kc*32 + hi*16) ^ ((row0 & 7) << 4)));
        accS0 = __builtin_amdgcn_mfma_f32_32x32x16_bf16(kf0, qf[kc], accS0, 0, 0, 0);
        const int row1 = 32 + l31;
        const bf16x8 kf1 = *(const bf16x8*)(KsB + row1 * 128 +
                            ((kc*32 + hi*16) ^ ((row1 & 7) << 4)));
        accS1 = __builtin_amdgcn_mfma_f32_32x32x16_bf16(kf1, qf[kc], accS1, 0, 0, 0);
      }
      __builtin_amdgcn_s_setprio(0);

      const unsigned va = vbase + (p & 1) * 16384 + half * 8192;
      s16x4 vlo[2][4], vhi[2][4];
      #pragma unroll
      for (int dblk = 0; dblk < 2; dblk++) {
        #pragma unroll
        for (int kc = 0; kc < 4; kc++) {
          asm volatile("ds_read_b64_tr_b16 %0, %2 offset:%3\n\t"
                       "ds_read_b64_tr_b16 %1, %2 offset:%4"
                       : "=v"(vlo[dblk][kc]), "=v"(vhi[dblk][kc])
                       : "v"(va), "i"(kc*2048 + dblk*256), "i"(kc*2048 + dblk*256 + 512)
                       : "memory");
        }
      }

      if (tflags[flagBase + kvt] == 0) {
        const size_t mrow = (size_t)(qw0 + l31) * L + kvt * 64;
        #pragma unroll
        for (int r = 0; r < 16; ++r) {
          const int kvr = (r & 3) + 8 * (r >> 2) + 4 * hi;
          if (mask[mrow + kvr] == 0)      accS0[r] = -1e9f;
          if (mask[mrow + 32 + kvr] == 0) accS1[r] = -1e9f;
        }
      }

      #pragma unroll
      for (int r = 0; r < 16; ++r) {
        accS0[r] = __builtin_amdgcn_exp2f(accS0[r]);
        accS1[r] = __builtin_amdgcn_exp2f(accS1[r]);
      }

      union U8 { uint32_t u[4]; bf16x8 v; };
      bf16x8 pa[4];
      #pragma unroll
      for (int b2 = 0; b2 < 2; b2++) {
        const f32x16& P = b2 ? accS1 : accS0;
        uint32_t t0 = cvtpk(P[0], P[1]),  t1 = cvtpk(P[4], P[5]);
        uint32_t u0 = cvtpk(P[2], P[3]),  u1 = cvtpk(P[6], P[7]);
        asm("v_permlane32_swap_b32 %0, %1" : "+v"(t0), "+v"(t1));
        asm("v_permlane32_swap_b32 %0, %1" : "+v"(u0), "+v"(u1));
        U8 f0; f0.u[0] = t0; f0.u[1] = u0; f0.u[2] = t1; f0.u[3] = u1;
        pa[2*b2] = f0.v;
        uint32_t v0 = cvtpk(P[8], P[9]),   v1 = cvtpk(P[12], P[13]);
        uint32_t w0 = cvtpk(P[10], P[11]), w1 = cvtpk(P[14], P[15]);
        asm("v_permlane32_swap_b32 %0, %1" : "+v"(v0), "+v"(v1));
        asm("v_permlane32_swap_b32 %0, %1" : "+v"(w0), "+v"(w1));
        U8 f1; f1.u[0] = v0; f1.u[1] = w0; f1.u[2] = v1; f1.u[3] = w1;
        pa[2*b2+1] = f1.v;
      }

      asm volatile("s_waitcnt lgkmcnt(0)" ::: "memory");
      __builtin_amdgcn_sched_barrier(0);
      __builtin_amdgcn_s_setprio(1);
      #pragma unroll
      for (int kc = 0; kc < 4; kc++) {
        const bf16x8 bv0 = __builtin_shufflevector(vlo[0][kc], vhi[0][kc],
                                                   0, 1, 2, 3, 4, 5, 6, 7);
        accO0 = __builtin_amdgcn_mfma_f32_32x32x16_bf16(pa[kc], bv0, accO0, 0, 0, 0);
        const bf16x8 bv1 = __builtin_shufflevector(vlo[1][kc], vhi[1][kc],
                                                   0, 1, 2, 3, 4, 5, 6, 7);
        accO1 = __builtin_amdgcn_mfma_f32_32x32x16_bf16(pa[kc], bv1, accO1, 0, 0, 0);
        accL  = __builtin_amdgcn_mfma_f32_32x32x16_bf16(pa[kc], onef, accL, 0, 0, 0);
      }
      __builtin_amdgcn_s_setprio(0);
    }
  }

  #pragma unroll
  for (int r = 0; r < 16; ++r) {
    const int qr = (r & 3) + 8 * (r >> 2) + 4 * hi;
    const float inv = 1.0f / accL[r];
    const size_t row = (size_t)b * L + qw0 + qr;
    AO[row * 1024 + h*64 +      l31] = f2bf(accO0[r] * inv);
    AO[row * 1024 + h*64 + 32 + l31] = f2bf(accO1[r] * inv);
  }
#undef STAGE2
}

extern "C" void kernel_launch(void* const* d_in, const int* in_sizes, int n_in,
                              void* d_out, int out_size, void* d_ws, size_t ws_size,
                              hipStream_t stream) {
  const float* q    = (const float*)d_in[0];
  const float* k    = (const float*)d_in[1];
  const float* v    = (const float*)d_in[2];
  const int*   mask = (const int*)d_in[3];
  const float* w_q  = (const float*)d_in[4];
  const float* w_k  = (const float*)d_in[5];
  const float* w_v  = (const float*)d_in[6];
  const float* w_o  = (const float*)d_in[7];
  const float* ln_g = (const float*)d_in[8];
  const float* ln_b = (const float*)d_in[9];
  float* out = (float*)d_out;

  char* ws = (char*)d_ws;
  const size_t MB = (size_t)1 << 20;
  ushort* qn  = (ushort*)(ws + 0*MB);
  ushort* kb  = (ushort*)(ws + 8*MB);    // dead after QKV GEMM; tflags reuses it
  ushort* vb  = (ushort*)(ws + 16*MB);
  ushort* wqb = (ushort*)(ws + 24*MB);
  ushort* wkb = (ushort*)(ws + 26*MB);
  ushort* wvb = (ushort*)(ws + 28*MB);
  ushort* wob = (ushort*)(ws + 30*MB);
  ushort* Qp  = (ushort*)(ws + 32*MB);
  ushort* Kp  = (ushort*)(ws + 40*MB);
  ushort* Vp  = (ushort*)(ws + 48*MB);
  ushort* AO  = (ushort*)(ws + 56*MB);
  int* tflags = (int*)(ws + 8*MB);       // written after gemm3 consumed kb

  const float QSCALE = 0.125f * 1.44269504089f;   // 1/sqrt(64) * log2(e)

  prep_kernel<<<16384, 256, 0, stream>>>(
      q, k, v, w_q, w_k, w_v, w_o, ln_g, ln_b,
      qn, kb, vb, wqb, wkb, wvb, wob);

  gemm3<<<768, 256, 0, stream>>>(
      qn, wqb, Qp, kb, wkb, Kp, vb, wvb, Vp, QSCALE);

  mask_flags<<<dim3(32, 32), 256, 0, stream>>>(mask, tflags);

  flash_attn<<<512, 256, 0, stream>>>(Qp, Kp, Vp, mask, tflags, AO);

  gemm_bm64<<<512, 256, 0, stream>>>(AO, wob, out, q);
}

// Round 12
// 133.651 us; speedup vs baseline: 1.2312x; 1.0854x over previous
//
#include <hip/hip_runtime.h>
#include <stdint.h>

typedef __attribute__((ext_vector_type(8))) short bf16x8;
typedef __attribute__((ext_vector_type(4))) short s16x4;
typedef __attribute__((ext_vector_type(4))) float f32x4;
typedef __attribute__((ext_vector_type(16))) float f32x16;

__device__ __forceinline__ ushort f2bf(float f) {
  union { float f; uint32_t u; } c; c.f = f;
  uint32_t r = (c.u + 0x7fffu + ((c.u >> 16) & 1u)) >> 16;
  return (ushort)r;
}

__device__ __forceinline__ void gload16(const void* g, void* l) {
  __builtin_amdgcn_global_load_lds(
      (const __attribute__((address_space(1))) void*)g,
      (__attribute__((address_space(3))) void*)l, 16, 0, 0);
}

__device__ __forceinline__ unsigned lds_addr(const void* p) {
  return (unsigned)(uintptr_t)(__attribute__((address_space(3))) const char*)p;
}

__device__ __forceinline__ uint32_t cvtpk(float lo, float hi) {
  uint32_t d;
  asm("v_cvt_pk_bf16_f32 %0, %1, %2" : "=v"(d) : "v"(lo), "v"(hi));
  return d;
}

// ---------------- fused prep: LN(q) + cast k,v + cast 4 weights ----------------
__global__ __launch_bounds__(256) void prep_kernel(
    const float* __restrict__ q, const float* __restrict__ k,
    const float* __restrict__ v, const float* __restrict__ w_q,
    const float* __restrict__ w_k, const float* __restrict__ w_v,
    const float* __restrict__ w_o, const float* __restrict__ ln_g,
    const float* __restrict__ ln_b,
    ushort* __restrict__ qn, ushort* __restrict__ kb, ushort* __restrict__ vb,
    ushort* __restrict__ wqb, ushort* __restrict__ wkb,
    ushort* __restrict__ wvb, ushort* __restrict__ wob) {
  const int bid = blockIdx.x;
  const int t = threadIdx.x;
  if (bid < 4096) {
    const int row = bid;
    const float4 val = ((const float4*)(q + (size_t)row * 1024))[t];
    float s  = val.x + val.y + val.z + val.w;
    float s2 = val.x*val.x + val.y*val.y + val.z*val.z + val.w*val.w;
    #pragma unroll
    for (int off = 1; off < 64; off <<= 1) {
      s  += __shfl_xor(s,  off);
      s2 += __shfl_xor(s2, off);
    }
    __shared__ float red[8];
    const int wave = t >> 6, lane = t & 63;
    if (lane == 0) { red[wave*2] = s; red[wave*2+1] = s2; }
    __syncthreads();
    s  = red[0] + red[2] + red[4] + red[6];
    s2 = red[1] + red[3] + red[5] + red[7];
    const float mu = s * (1.0f/1024.0f);
    const float var = s2 * (1.0f/1024.0f) - mu*mu;
    const float rs = rsqrtf(var + 1e-6f);
    const float4 gg = ((const float4*)ln_g)[t];
    const float4 bb = ((const float4*)ln_b)[t];
    ushort4 o;
    o.x = f2bf((val.x - mu) * rs * gg.x + bb.x);
    o.y = f2bf((val.y - mu) * rs * gg.y + bb.y);
    o.z = f2bf((val.z - mu) * rs * gg.z + bb.z);
    o.w = f2bf((val.w - mu) * rs * gg.w + bb.w);
    ((ushort4*)(qn + (size_t)row * 1024))[t] = o;
    return;
  }
  const float* in; ushort* out; int i;
  if (bid < 12288) {
    const int idx = bid - 4096;
    const bool isv = idx >= 4096;
    in  = isv ? v : k;
    out = isv ? vb : kb;
    i = (idx & 4095) * 256 + t;
  } else {
    const int idx = bid - 12288;
    const int w = idx >> 10;
    in  = w == 0 ? w_q : (w == 1 ? w_k : (w == 2 ? w_v : w_o));
    out = w == 0 ? wqb : (w == 1 ? wkb : (w == 2 ? wvb : wob));
    i = (idx & 1023) * 256 + t;
  }
  const float4 val = ((const float4*)in)[i];
  ushort4 o;
  o.x = f2bf(val.x); o.y = f2bf(val.y); o.z = f2bf(val.z); o.w = f2bf(val.w);
  ((ushort4*)out)[i] = o;
}

// ---------------- mask tile flags (64x64 granularity) ----------------
__global__ __launch_bounds__(256) void mask_flags(
    const int* __restrict__ mask, int* __restrict__ flags) {
  const int qt = blockIdx.y, kt = blockIdx.x;
  const int t = threadIdx.x;
  const int* p = mask + (size_t)(qt * 64 + (t >> 2)) * 2048 + kt * 64 + (t & 3) * 16;
  int ok = 1;
  #pragma unroll
  for (int i = 0; i < 4; i++) {
    const int4 m = ((const int4*)p)[i];
    ok &= (m.x != 0) & (m.y != 0) & (m.z != 0) & (m.w != 0);
  }
  __shared__ int sok;
  if (t == 0) sok = 1;
  __syncthreads();
  if (!ok) atomicAnd(&sok, 0);
  __syncthreads();
  if (t == 0) flags[qt * 32 + kt] = sok;
}

// ---------------- QKV GEMM: 3 LDS buffers (48KB -> 3 blocks/CU, one round) -----
// XCD-swizzled grid + T2 LDS XOR-swizzle (R11-proven). vmcnt(4) counted pipeline:
// at step s: wait(4) -> step-s loads landed (s+1 in flight); barrier; issue s+2
// into buffer (s+2)%3 == (s-1)%3, safe because barrier proves compute(s-1) done.
__global__ __launch_bounds__(256) void gemm3(
    const ushort* __restrict__ A0, const ushort* __restrict__ W0, ushort* __restrict__ C0,
    const ushort* __restrict__ A1, const ushort* __restrict__ W1, ushort* __restrict__ C1,
    const ushort* __restrict__ A2, const ushort* __restrict__ W2, ushort* __restrict__ C2,
    float qscale) {
  __shared__ ushort As[3][4096];
  __shared__ ushort Bs[3][4096];
  const int t = threadIdx.x, lane = t & 63, wave = t >> 6;
  const int wr = wave >> 1, wc = wave & 1;
  const int lr = lane & 15, lg = lane >> 4;
  const int lin = blockIdx.x;
  const int swz = (lin & 7) * 96 + (lin >> 3);     // bijective: 768 = 8*96
  const int brow = ((swz >> 3) & 31) * 128, bcol = (swz & 7) * 128;
  const int z = swz >> 8;
  const ushort* A = z == 0 ? A0 : (z == 1 ? A1 : A2);
  const ushort* W = z == 0 ? W0 : (z == 1 ? W1 : W2);
  ushort*      C = z == 0 ? C0 : (z == 1 ? C1 : C2);
  const float sc = (z == 0) ? qscale : 1.0f;
  f32x4 acc[4][4] = {};
  const int r_ = t >> 2, cx = (t & 3) ^ ((r_ >> 1) & 3);   // source chunk XOR
  const ushort* gA = A + (size_t)(brow + r_) * 1024 + cx * 8;
  const ushort* gB = W + (size_t)(bcol + r_) * 1024 + cx * 8;
  const int woff = wave * 1024;
  const int xA = ((lr >> 1) & 3) * 8;                      // read-side XOR (ushorts)

#define G_ISSUE(S) { \
    char* la = (char*)As + ((S) % 3) * 8192 + woff; \
    char* lb = (char*)Bs + ((S) % 3) * 8192 + woff; \
    const ushort* ap_ = gA + (S) * 32; \
    const ushort* bp_ = gB + (S) * 32; \
    gload16(ap_, la); gload16(ap_ + 64 * 1024, la + 4096); \
    gload16(bp_, lb); gload16(bp_ + 64 * 1024, lb + 4096); }

#define G_COMPUTE(S) { \
    const ushort* as_ = As[(S) % 3]; \
    const ushort* bs_ = Bs[(S) % 3]; \
    bf16x8 af[4], bfr[4]; \
    _Pragma("unroll") for (int i = 0; i < 4; i++) \
      af[i]  = *(const bf16x8*)&as_[(wr*64 + i*16 + lr) * 32 + ((lg*8) ^ xA)]; \
    _Pragma("unroll") for (int i = 0; i < 4; i++) \
      bfr[i] = *(const bf16x8*)&bs_[(wc*64 + i*16 + lr) * 32 + ((lg*8) ^ xA)]; \
    _Pragma("unroll") for (int mi = 0; mi < 4; mi++) \
      _Pragma("unroll") for (int ni = 0; ni < 4; ni++) \
        acc[mi][ni] = __builtin_amdgcn_mfma_f32_16x16x32_bf16(af[mi], bfr[ni], acc[mi][ni], 0, 0, 0); }

  G_ISSUE(0); G_ISSUE(1);
  for (int s = 0; s < 30; ++s) {
    asm volatile("s_waitcnt vmcnt(4)" ::: "memory");
    __builtin_amdgcn_s_barrier();
    G_ISSUE(s + 2);
    G_COMPUTE(s);
  }
  asm volatile("s_waitcnt vmcnt(4)" ::: "memory");
  __builtin_amdgcn_s_barrier();
  G_COMPUTE(30);
  asm volatile("s_waitcnt vmcnt(0)" ::: "memory");
  __builtin_amdgcn_s_barrier();
  G_COMPUTE(31);
#undef G_ISSUE
#undef G_COMPUTE

  #pragma unroll
  for (int mi = 0; mi < 4; mi++) {
    #pragma unroll
    for (int ni = 0; ni < 4; ni++) {
      #pragma unroll
      for (int r = 0; r < 4; r++) {
        const size_t row = brow + wr*64 + mi*16 + lg*4 + r;
        const size_t col = bcol + wc*64 + ni*16 + lr;
        C[row * 1024 + col] = f2bf(acc[mi][ni][r] * sc);
      }
    }
  }
}

// ---------------- Final GEMM: BM=64, XCD+T2 swizzles, fused residual -----------
__global__ __launch_bounds__(256) void gemm_bm64(
    const ushort* __restrict__ A, const ushort* __restrict__ W,
    float* __restrict__ Cf, const float* __restrict__ resid) {
  __shared__ ushort As[4][2048];
  __shared__ ushort Bs[4][4096];
  const int t = threadIdx.x, lane = t & 63, wave = t >> 6;
  const int wr = wave >> 1, wc = wave & 1;
  const int lr = lane & 15, lg = lane >> 4;
  const int lin = blockIdx.x;
  const int swz = (lin & 7) * 64 + (lin >> 3);     // bijective: 512 = 8*64
  const int brow = (swz >> 3) * 64, bcol = (swz & 7) * 128;
  f32x4 acc[2][4] = {};
  const int r_ = t >> 2, cx = (t & 3) ^ ((r_ >> 1) & 3);
  const ushort* gA = A + (size_t)(brow + r_) * 1024 + cx * 8;
  const ushort* gB = W + (size_t)(bcol + r_) * 1024 + cx * 8;
  const int woff = wave * 1024;
  const int xA = ((lr >> 1) & 3) * 8;

#define G_ISSUE(S) { \
    char* la = (char*)As + ((S) & 3) * 4096 + woff; \
    char* lb = (char*)Bs + ((S) & 3) * 8192 + woff; \
    const ushort* ap_ = gA + (S) * 32; \
    const ushort* bp_ = gB + (S) * 32; \
    gload16(ap_, la); \
    gload16(bp_, lb); gload16(bp_ + 64 * 1024, lb + 4096); }

#define G_COMPUTE(S) { \
    const ushort* as_ = As[(S) & 3]; \
    const ushort* bs_ = Bs[(S) & 3]; \
    bf16x8 af[2], bfr[4]; \
    _Pragma("unroll") for (int i = 0; i < 2; i++) \
      af[i]  = *(const bf16x8*)&as_[(wr*32 + i*16 + lr) * 32 + ((lg*8) ^ xA)]; \
    _Pragma("unroll") for (int i = 0; i < 4; i++) \
      bfr[i] = *(const bf16x8*)&bs_[(wc*64 + i*16 + lr) * 32 + ((lg*8) ^ xA)]; \
    _Pragma("unroll") for (int mi = 0; mi < 2; mi++) \
      _Pragma("unroll") for (int ni = 0; ni < 4; ni++) \
        acc[mi][ni] = __builtin_amdgcn_mfma_f32_16x16x32_bf16(af[mi], bfr[ni], acc[mi][ni], 0, 0, 0); }

  G_ISSUE(0); G_ISSUE(1); G_ISSUE(2);
  for (int s = 0; s < 30; ++s) {
    asm volatile("s_waitcnt vmcnt(6)" ::: "memory");
    __builtin_amdgcn_s_barrier();
    if (s < 29) G_ISSUE(s + 3);
    G_COMPUTE(s);
  }
  asm volatile("s_waitcnt vmcnt(3)" ::: "memory");
  __builtin_amdgcn_s_barrier();
  G_COMPUTE(30);
  asm volatile("s_waitcnt vmcnt(0)" ::: "memory");
  __builtin_amdgcn_s_barrier();
  G_COMPUTE(31);
#undef G_ISSUE
#undef G_COMPUTE

  #pragma unroll
  for (int mi = 0; mi < 2; mi++) {
    #pragma unroll
    for (int ni = 0; ni < 4; ni++) {
      #pragma unroll
      for (int r = 0; r < 4; r++) {
        const size_t row = brow + wr*32 + mi*16 + lg*4 + r;
        const size_t col = bcol + wc*64 + ni*16 + lr;
        Cf[row * 1024 + col] = acc[mi][ni][r] + resid[row * 1024 + col];
      }
    }
  }
}

// ---------------- Flash attention: R10-proven paired-tile body + XCD swizzle ---
__global__ __launch_bounds__(256) void flash_attn(
    const ushort* __restrict__ Qp, const ushort* __restrict__ Kp,
    const ushort* __restrict__ Vp, const int* __restrict__ mask,
    const int* __restrict__ tflags, ushort* __restrict__ AO) {
  const int L = 2048;
  const int lin = blockIdx.x;
  const int swzb = (lin & 7) * 64 + (lin >> 3);    // bijective: 512 = 8*64
  const int qb = swzb & 15, h = (swzb >> 4) & 15, b = swzb >> 8;
  const int t = threadIdx.x, lane = t & 63, wave = t >> 6;
  const int l31 = lane & 31, hi = lane >> 5;
  __shared__ ushort Ks[2][8192];   // pair buffer: 2 tiles x 8KB
  __shared__ ushort Vs[2][8192];
  const size_t base = (size_t)b * L * 1024 + h * 64;
  const int qw0 = qb * 128 + wave * 32;

  bf16x8 qf[4];
  #pragma unroll
  for (int kc = 0; kc < 4; kc++)
    qf[kc] = *(const bf16x8*)(Qp + base + (size_t)(qw0 + l31) * 1024 + kc*16 + hi*8);

  f32x16 accO0 = {0.f}, accO1 = {0.f}, accL = {0.f};
  const bf16x8 onef = {16256, 16256, 16256, 16256, 16256, 16256, 16256, 16256};

  const int r3 = (lane >> 3) & 7;
  const int c3 = (lane & 7) ^ r3;
  const ushort* gK = Kp + base + (size_t)(wave*8 + r3) * 1024 + c3 * 8;
  const int sv = t >> 3, hv = t & 7;
  const int vkv = (sv >> 2) * 4 + (hv >> 1);
  const int vd  = (sv & 3) * 16 + (hv & 1) * 8;
  const ushort* gV = Vp + base + (size_t)vkv * 1024 + vd;

  const unsigned vbase = lds_addr((const char*)Vs) + hi * 1024 +
                         ((lane >> 4) & 1) * 128 + (lane & 15) * 8;

#define STAGE2(P, BUF) { \
    char* kb_ = (char*)Ks[BUF] + wave * 1024; \
    const ushort* gk_ = gK + (size_t)(2*(P)) * 65536; \
    gload16(gk_,             kb_);         gload16(gk_ + 32*1024, kb_ + 4096); \
    gload16(gk_ + 64*1024,   kb_ + 8192);  gload16(gk_ + 96*1024, kb_ + 12288); \
    char* vb_ = (char*)Vs[BUF] + wave * 1024; \
    const ushort* gv_ = gV + (size_t)(2*(P)) * 65536; \
    gload16(gv_,             vb_);         gload16(gv_ + 32*1024, vb_ + 4096); \
    gload16(gv_ + 64*1024,   vb_ + 8192);  gload16(gv_ + 96*1024, vb_ + 12288); }

  STAGE2(0, 0);
  const int flagBase = (qb * 2 + (wave >> 1)) * 32;

  for (int p = 0; p < 16; ++p) {
    asm volatile("s_waitcnt vmcnt(0)" ::: "memory");
    __builtin_amdgcn_s_barrier();
    if (p + 1 < 16) { STAGE2(p + 1, (p + 1) & 1); }

    #pragma unroll
    for (int half = 0; half < 2; ++half) {
      const int kvt = 2*p + half;
      const char* KsB = (const char*)Ks[p & 1] + half * 8192;
      f32x16 accS0 = {0.f}, accS1 = {0.f};
      __builtin_amdgcn_s_setprio(1);
      #pragma unroll
      for (int kc = 0; kc < 4; kc++) {
        const int row0 = l31;
        const bf16x8 kf0 = *(const bf16x8*)(KsB + row0 * 128 +
                            ((kc*32 + hi*16) ^ ((row0 & 7) << 4)));
        accS0 = __builtin_amdgcn_mfma_f32_32x32x16_bf16(kf0, qf[kc], accS0, 0, 0, 0);
        const int row1 = 32 + l31;
        const bf16x8 kf1 = *(const bf16x8*)(KsB + row1 * 128 +
                            ((kc*32 + hi*16) ^ ((row1 & 7) << 4)));
        accS1 = __builtin_amdgcn_mfma_f32_32x32x16_bf16(kf1, qf[kc], accS1, 0, 0, 0);
      }
      __builtin_amdgcn_s_setprio(0);

      const unsigned va = vbase + (p & 1) * 16384 + half * 8192;
      s16x4 vlo[2][4], vhi[2][4];
      #pragma unroll
      for (int dblk = 0; dblk < 2; dblk++) {
        #pragma unroll
        for (int kc = 0; kc < 4; kc++) {
          asm volatile("ds_read_b64_tr_b16 %0, %2 offset:%3\n\t"
                       "ds_read_b64_tr_b16 %1, %2 offset:%4"
                       : "=v"(vlo[dblk][kc]), "=v"(vhi[dblk][kc])
                       : "v"(va), "i"(kc*2048 + dblk*256), "i"(kc*2048 + dblk*256 + 512)
                       : "memory");
        }
      }

      if (tflags[flagBase + kvt] == 0) {
        const size_t mrow = (size_t)(qw0 + l31) * L + kvt * 64;
        #pragma unroll
        for (int r = 0; r < 16; ++r) {
          const int kvr = (r & 3) + 8 * (r >> 2) + 4 * hi;
          if (mask[mrow + kvr] == 0)      accS0[r] = -1e9f;
          if (mask[mrow + 32 + kvr] == 0) accS1[r] = -1e9f;
        }
      }

      #pragma unroll
      for (int r = 0; r < 16; ++r) {
        accS0[r] = __builtin_amdgcn_exp2f(accS0[r]);
        accS1[r] = __builtin_amdgcn_exp2f(accS1[r]);
      }

      union U8 { uint32_t u[4]; bf16x8 v; };
      bf16x8 pa[4];
      #pragma unroll
      for (int b2 = 0; b2 < 2; b2++) {
        const f32x16& P = b2 ? accS1 : accS0;
        uint32_t t0 = cvtpk(P[0], P[1]),  t1 = cvtpk(P[4], P[5]);
        uint32_t u0 = cvtpk(P[2], P[3]),  u1 = cvtpk(P[6], P[7]);
        asm("v_permlane32_swap_b32 %0, %1" : "+v"(t0), "+v"(t1));
        asm("v_permlane32_swap_b32 %0, %1" : "+v"(u0), "+v"(u1));
        U8 f0; f0.u[0] = t0; f0.u[1] = u0; f0.u[2] = t1; f0.u[3] = u1;
        pa[2*b2] = f0.v;
        uint32_t v0 = cvtpk(P[8], P[9]),   v1 = cvtpk(P[12], P[13]);
        uint32_t w0 = cvtpk(P[10], P[11]), w1 = cvtpk(P[14], P[15]);
        asm("v_permlane32_swap_b32 %0, %1" : "+v"(v0), "+v"(v1));
        asm("v_permlane32_swap_b32 %0, %1" : "+v"(w0), "+v"(w1));
        U8 f1; f1.u[0] = v0; f1.u[1] = w0; f1.u[2] = v1; f1.u[3] = w1;
        pa[2*b2+1] = f1.v;
      }

      asm volatile("s_waitcnt lgkmcnt(0)" ::: "memory");
      __builtin_amdgcn_sched_barrier(0);
      __builtin_amdgcn_s_setprio(1);
      #pragma unroll
      for (int kc = 0; kc < 4; kc++) {
        const bf16x8 bv0 = __builtin_shufflevector(vlo[0][kc], vhi[0][kc],
                                                   0, 1, 2, 3, 4, 5, 6, 7);
        accO0 = __builtin_amdgcn_mfma_f32_32x32x16_bf16(pa[kc], bv0, accO0, 0, 0, 0);
        const bf16x8 bv1 = __builtin_shufflevector(vlo[1][kc], vhi[1][kc],
                                                   0, 1, 2, 3, 4, 5, 6, 7);
        accO1 = __builtin_amdgcn_mfma_f32_32x32x16_bf16(pa[kc], bv1, accO1, 0, 0, 0);
        accL  = __builtin_amdgcn_mfma_f32_32x32x16_bf16(pa[kc], onef, accL, 0, 0, 0);
      }
      __builtin_amdgcn_s_setprio(0);
    }
  }

  #pragma unroll
  for (int r = 0; r < 16; ++r) {
    const int qr = (r & 3) + 8 * (r >> 2) + 4 * hi;
    const float inv = 1.0f / accL[r];
    const size_t row = (size_t)b * L + qw0 + qr;
    AO[row * 1024 + h*64 +      l31] = f2bf(accO0[r] * inv);
    AO[row * 1024 + h*64 + 32 + l31] = f2bf(accO1[r] * inv);
  }
#undef STAGE2
}

extern "C" void kernel_launch(void* const* d_in, const int* in_sizes, int n_in,
                              void* d_out, int out_size, void* d_ws, size_t ws_size,
                              hipStream_t stream) {
  const float* q    = (const float*)d_in[0];
  const float* k    = (const float*)d_in[1];
  const float* v    = (const float*)d_in[2];
  const int*   mask = (const int*)d_in[3];
  const float* w_q  = (const float*)d_in[4];
  const float* w_k  = (const float*)d_in[5];
  const float* w_v  = (const float*)d_in[6];
  const float* w_o  = (const float*)d_in[7];
  const float* ln_g = (const float*)d_in[8];
  const float* ln_b = (const float*)d_in[9];
  float* out = (float*)d_out;

  char* ws = (char*)d_ws;
  const size_t MB = (size_t)1 << 20;
  ushort* qn  = (ushort*)(ws + 0*MB);
  ushort* kb  = (ushort*)(ws + 8*MB);    // dead after QKV GEMM; tflags reuses it
  ushort* vb  = (ushort*)(ws + 16*MB);
  ushort* wqb = (ushort*)(ws + 24*MB);
  ushort* wkb = (ushort*)(ws + 26*MB);
  ushort* wvb = (ushort*)(ws + 28*MB);
  ushort* wob = (ushort*)(ws + 30*MB);
  ushort* Qp  = (ushort*)(ws + 32*MB);
  ushort* Kp  = (ushort*)(ws + 40*MB);
  ushort* Vp  = (ushort*)(ws + 48*MB);
  ushort* AO  = (ushort*)(ws + 56*MB);
  int* tflags = (int*)(ws + 8*MB);       // written after gemm3 consumed kb

  const float QSCALE = 0.125f * 1.44269504089f;   // 1/sqrt(64) * log2(e)

  prep_kernel<<<16384, 256, 0, stream>>>(
      q, k, v, w_q, w_k, w_v, w_o, ln_g, ln_b,
      qn, kb, vb, wqb, wkb, wvb, wob);

  gemm3<<<768, 256, 0, stream>>>(
      qn, wqb, Qp, kb, wkb, Kp, vb, wvb, Vp, QSCALE);

  mask_flags<<<dim3(32, 32), 256, 0, stream>>>(mask, tflags);

  flash_attn<<<512, 256, 0, stream>>>(Qp, Kp, Vp, mask, tflags, AO);

  gemm_bm64<<<512, 256, 0, stream>>>(AO, wob, out, q);
}